// Round 1
// baseline (215.862 us; speedup 1.0000x reference)
//
#include <hip/hip_runtime.h>
#include <hip/hip_bf16.h>
#include <stdint.h>

#define B_ 2048
#define L_ 128
#define V_ 50000
#define D_ 128

typedef __attribute__((ext_vector_type(8))) short bf16x8;
typedef __attribute__((ext_vector_type(8))) unsigned short ushort8;
typedef __attribute__((ext_vector_type(4))) float f32x4;

__device__ inline unsigned short f2bf(float f) {
    union { float f; uint32_t u; } v; v.f = f;
    uint32_t u = v.u + 0x7FFFu + ((v.u >> 16) & 1u);   // RNE
    return (unsigned short)(u >> 16);
}
__device__ inline float bf2f(unsigned short h) {
    union { uint32_t u; float f; } v; v.u = ((uint32_t)h) << 16;
    return v.f;
}
__device__ inline float tanh_fast(float x) {
    float xc = fminf(fmaxf(x, -15.f), 15.f);
    float z = __expf(2.f * xc);
    return (z - 1.f) / (z + 1.f);
}

// ---------------- kernel 0: aT_bf16[n][d] = bf16(attn_a[d][n]) ----------------
__global__ __launch_bounds__(256) void k_prep(const float* __restrict__ a,
                                              unsigned short* __restrict__ aT) {
    int i = blockIdx.x * 256 + threadIdx.x;   // 16384 elems
    int d = i >> 7, n = i & 127;
    aT[n * 128 + d] = f2bf(a[d * 128 + n]);
}

// ---------------- kernel 1: user_bf16[b][d] ----------------
// one block per b; 256 threads = 4 waves
__global__ __launch_bounds__(256) void k_user(
    const int* __restrict__ ids, const int* __restrict__ msk,
    const float* __restrict__ emb, const unsigned short* __restrict__ aT,
    const float* __restrict__ bvec, unsigned short* __restrict__ user_bf) {
    __shared__ __align__(16) unsigned short lh[128 * 128];  // h tile, swizzled
    __shared__ __align__(16) unsigned short la[128 * 128];  // aT tile, swizzled
    __shared__ float l_e[128];
    __shared__ float l_attn[128];
    __shared__ float l_p[256];

    int b = blockIdx.x;
    int t = threadIdx.x;

    // stage h = emb[ids[b,:]] -> bf16 LDS (XOR swizzle on ushort index: c ^ ((row&7)<<3))
    {
        int row = t >> 1, half = t & 1;
        int id = ids[b * L_ + row];
        const float* src = emb + (size_t)id * D_ + half * 64;
#pragma unroll
        for (int q = 0; q < 8; ++q) {
            float4 x0 = *(const float4*)(src + q * 8);
            float4 x1 = *(const float4*)(src + q * 8 + 4);
            ushort8 v;
            v[0] = f2bf(x0.x); v[1] = f2bf(x0.y); v[2] = f2bf(x0.z); v[3] = f2bf(x0.w);
            v[4] = f2bf(x1.x); v[5] = f2bf(x1.y); v[6] = f2bf(x1.z); v[7] = f2bf(x1.w);
            int c = half * 64 + q * 8;
            *(ushort8*)&lh[row * 128 + (c ^ ((row & 7) << 3))] = v;
        }
    }
    // stage aT (linear 32KB copy, swizzled dest)
#pragma unroll
    for (int i = 0; i < 8; ++i) {
        int chunk = t + i * 256;          // 2048 chunks of 8 ushorts
        int cus = chunk * 8;
        int row = cus >> 7, col = cus & 127;
        ushort8 v = *(const ushort8*)(aT + cus);
        *(ushort8*)&la[row * 128 + (col ^ ((row & 7) << 3))] = v;
    }
    __syncthreads();

    int wave = t >> 6, lane = t & 63, lo = lane & 15, hi = lane >> 4;

    // t = h @ a  via mfma 16x16x32 (M=128 rows of h, N=128, K=128)
    f32x4 acc[2][8] = {};
#pragma unroll
    for (int kk = 0; kk < 4; ++kk) {
        int kc = kk * 32 + hi * 8;   // k element offset
        bf16x8 afr[2];
#pragma unroll
        for (int mi = 0; mi < 2; ++mi) {
            int row = wave * 32 + mi * 16 + lo;
            afr[mi] = *(const bf16x8*)&lh[row * 128 + (kc ^ ((row & 7) << 3))];
        }
#pragma unroll
        for (int nj = 0; nj < 8; ++nj) {
            int col = nj * 16 + lo;
            bf16x8 bfr = *(const bf16x8*)&la[col * 128 + (kc ^ ((col & 7) << 3))];
            acc[0][nj] = __builtin_amdgcn_mfma_f32_16x16x32_bf16(afr[0], bfr, acc[0][nj], 0, 0, 0);
            acc[1][nj] = __builtin_amdgcn_mfma_f32_16x16x32_bf16(afr[1], bfr, acc[1][nj], 0, 0, 0);
        }
    }

    // e[row] = sum_n tanh(t[row,n]) * bvec[n] ; C/D layout: col=lo, row=hi*4+reg
    float bv[8];
#pragma unroll
    for (int nj = 0; nj < 8; ++nj) bv[nj] = bvec[nj * 16 + lo];
#pragma unroll
    for (int mi = 0; mi < 2; ++mi) {
#pragma unroll
        for (int reg = 0; reg < 4; ++reg) {
            float p = 0.f;
#pragma unroll
            for (int nj = 0; nj < 8; ++nj) p += tanh_fast(acc[mi][nj][reg]) * bv[nj];
            p += __shfl_xor(p, 1); p += __shfl_xor(p, 2);
            p += __shfl_xor(p, 4); p += __shfl_xor(p, 8);
            int row = wave * 32 + mi * 16 + hi * 4 + reg;
            if (lo == 0) l_e[row] = p;
        }
    }
    __syncthreads();

    if (t < 128) {
        float e = l_e[t];
        float at = 0.f;
        if (msk[b * L_ + t]) at = 1.f / (1.f + __expf(-e));
        l_attn[t] = at;
    }
    __syncthreads();

    // user[d] = sum_l attn[l] * h[l][d]
    {
        int d = t & 127, half = t >> 7;
        float s = 0.f;
#pragma unroll 8
        for (int l = half * 64; l < half * 64 + 64; ++l)
            s += l_attn[l] * bf2f(lh[l * 128 + (d ^ ((l & 7) << 3))]);
        l_p[t] = s;
    }
    __syncthreads();
    if (t < 128) {
        float u = l_p[t] + l_p[t + 128];
        user_bf[b * 128 + t] = f2bf(u);
    }
}

// ---------------- kernel 2: logits = user_bf16 @ emb^T + bias ----------------
// grid (16 M-tiles, 391 N-tiles), 256 threads = 4 waves, tile 128x128, K=128
__global__ __launch_bounds__(256) void k_logits(
    const unsigned short* __restrict__ user_bf, const float* __restrict__ emb,
    const float* __restrict__ bias, float* __restrict__ out) {
    __shared__ __align__(16) unsigned short lb[128 * 128];  // emb tile [n][k] bf16 swizzled

    int t = threadIdx.x;
    int m0 = blockIdx.x * 128;
    int n0 = blockIdx.y * 128;

    // stage B: emb rows n0..n0+127 fp32 -> bf16 LDS (guard tail rows -> 0)
    {
        int r = t >> 1, half = t & 1;
        int n = n0 + r;
        if (n < V_) {
            const float* src = emb + (size_t)n * D_ + half * 64;
#pragma unroll
            for (int q = 0; q < 8; ++q) {
                float4 x0 = *(const float4*)(src + q * 8);
                float4 x1 = *(const float4*)(src + q * 8 + 4);
                ushort8 v;
                v[0] = f2bf(x0.x); v[1] = f2bf(x0.y); v[2] = f2bf(x0.z); v[3] = f2bf(x0.w);
                v[4] = f2bf(x1.x); v[5] = f2bf(x1.y); v[6] = f2bf(x1.z); v[7] = f2bf(x1.w);
                int c = half * 64 + q * 8;
                *(ushort8*)&lb[r * 128 + (c ^ ((r & 7) << 3))] = v;
            }
        } else {
            ushort8 z = {0, 0, 0, 0, 0, 0, 0, 0};
#pragma unroll
            for (int q = 0; q < 8; ++q) {
                int c = half * 64 + q * 8;
                *(ushort8*)&lb[r * 128 + (c ^ ((r & 7) << 3))] = z;
            }
        }
    }

    int wave = t >> 6, lane = t & 63, lo = lane & 15, hi = lane >> 4;

    // A fragments straight from global (user_bf is 512KB, cache-resident)
    bf16x8 afr[2][4];
#pragma unroll
    for (int mi = 0; mi < 2; ++mi) {
        int row = m0 + wave * 32 + mi * 16 + lo;
        const unsigned short* ap = user_bf + row * 128;
#pragma unroll
        for (int kk = 0; kk < 4; ++kk)
            afr[mi][kk] = *(const bf16x8*)(ap + kk * 32 + hi * 8);
    }
    __syncthreads();

    f32x4 acc[2][8] = {};
#pragma unroll
    for (int kk = 0; kk < 4; ++kk) {
        int kc = kk * 32 + hi * 8;
#pragma unroll
        for (int nj = 0; nj < 8; ++nj) {
            int col = nj * 16 + lo;
            bf16x8 bfr = *(const bf16x8*)&lb[col * 128 + (kc ^ ((col & 7) << 3))];
            acc[0][nj] = __builtin_amdgcn_mfma_f32_16x16x32_bf16(afr[0][kk], bfr, acc[0][nj], 0, 0, 0);
            acc[1][nj] = __builtin_amdgcn_mfma_f32_16x16x32_bf16(afr[1][kk], bfr, acc[1][nj], 0, 0, 0);
        }
    }

    // epilogue: + bias, guarded store (C/D: col=lo, row=hi*4+reg)
    float bv[8];
#pragma unroll
    for (int nj = 0; nj < 8; ++nj) {
        int v = n0 + nj * 16 + lo;
        bv[nj] = (v < V_) ? bias[v] : 0.f;
    }
#pragma unroll
    for (int mi = 0; mi < 2; ++mi) {
#pragma unroll
        for (int nj = 0; nj < 8; ++nj) {
            int col = n0 + nj * 16 + lo;
            if (col < V_) {
                int rowb = m0 + wave * 32 + mi * 16 + hi * 4;
#pragma unroll
                for (int reg = 0; reg < 4; ++reg) {
                    out[(size_t)(rowb + reg) * V_ + col] = acc[mi][nj][reg] + bv[nj];
                }
            }
        }
    }
}

extern "C" void kernel_launch(void* const* d_in, const int* in_sizes, int n_in,
                              void* d_out, int out_size, void* d_ws, size_t ws_size,
                              hipStream_t stream) {
    const int* ids      = (const int*)d_in[0];
    const int* msk      = (const int*)d_in[1];
    const float* emb    = (const float*)d_in[2];
    const float* attn_a = (const float*)d_in[3];
    const float* attn_b = (const float*)d_in[4];
    const float* rbias  = (const float*)d_in[5];
    float* out = (float*)d_out;

    unsigned short* aT      = (unsigned short*)d_ws;                    // 32 KB
    unsigned short* user_bf = (unsigned short*)((char*)d_ws + 32768);   // 512 KB

    k_prep<<<64, 256, 0, stream>>>(attn_a, aT);
    k_user<<<2048, 256, 0, stream>>>(ids, msk, emb, aT, attn_b, user_bf);
    k_logits<<<dim3(16, (V_ + 127) / 128), 256, 0, stream>>>(user_bf, emb, rbias, out);
}

// Round 2
// 211.302 us; speedup vs baseline: 1.0216x; 1.0216x over previous
//
#include <hip/hip_runtime.h>
#include <hip/hip_bf16.h>
#include <stdint.h>

#define B_ 2048
#define L_ 128
#define V_ 50000
#define D_ 128

typedef __attribute__((ext_vector_type(8))) short bf16x8;
typedef __attribute__((ext_vector_type(8))) unsigned short ushort8;
typedef __attribute__((ext_vector_type(4))) float f32x4;

__device__ inline unsigned short f2bf(float f) {
    union { float f; uint32_t u; } v; v.f = f;
    uint32_t u = v.u + 0x7FFFu + ((v.u >> 16) & 1u);   // RNE
    return (unsigned short)(u >> 16);
}
__device__ inline float bf2f(unsigned short h) {
    union { uint32_t u; float f; } v; v.u = ((uint32_t)h) << 16;
    return v.f;
}
__device__ inline float tanh_fast(float x) {
    float xc = fminf(fmaxf(x, -15.f), 15.f);
    float z = __expf(2.f * xc);
    return (z - 1.f) / (z + 1.f);
}

// ---------------- kernel 0: aT_bf16[n][d] = bf16(attn_a[d][n]) ----------------
__global__ __launch_bounds__(256) void k_prep(const float* __restrict__ a,
                                              unsigned short* __restrict__ aT) {
    int i = blockIdx.x * 256 + threadIdx.x;   // 16384 elems
    int d = i >> 7, n = i & 127;
    aT[n * 128 + d] = f2bf(a[d * 128 + n]);
}

// ---------------- kernel 0b: emb_bf[v][d] = bf16(emb[v][d]) ----------------
__global__ __launch_bounds__(256) void k_convE(const float* __restrict__ emb,
                                               unsigned short* __restrict__ emb_bf) {
    size_t i = ((size_t)blockIdx.x * 256 + threadIdx.x) * 8;  // 6,400,000 elems, grid exact
    float4 x0 = *(const float4*)(emb + i);
    float4 x1 = *(const float4*)(emb + i + 4);
    ushort8 v;
    v[0] = f2bf(x0.x); v[1] = f2bf(x0.y); v[2] = f2bf(x0.z); v[3] = f2bf(x0.w);
    v[4] = f2bf(x1.x); v[5] = f2bf(x1.y); v[6] = f2bf(x1.z); v[7] = f2bf(x1.w);
    *(ushort8*)(emb_bf + i) = v;
}

// ---------------- kernel 1: user_bf16[b][d] ----------------
// one block per b; 256 threads = 4 waves; aT fragments read straight from L2
__global__ __launch_bounds__(256) void k_user(
    const int* __restrict__ ids, const int* __restrict__ msk,
    const float* __restrict__ emb, const unsigned short* __restrict__ emb_bf,
    const unsigned short* __restrict__ aT,
    const float* __restrict__ bvec, unsigned short* __restrict__ user_bf,
    int use_bf) {
    __shared__ __align__(16) unsigned short lh[128 * 128];  // h tile, swizzled (32KB)
    __shared__ float l_e[128];
    __shared__ float l_attn[128];
    __shared__ float l_p[256];

    int b = blockIdx.x;
    int t = threadIdx.x;

    // stage h = emb[ids[b,:]] -> bf16 LDS (XOR swizzle on ushort index: c ^ ((row&7)<<3))
    {
        int row = t >> 1, half = t & 1;
        int id = ids[b * L_ + row];
        if (use_bf) {
            const unsigned short* src = emb_bf + (size_t)id * D_ + half * 64;
#pragma unroll
            for (int q = 0; q < 8; ++q) {
                ushort8 v = *(const ushort8*)(src + q * 8);
                int c = half * 64 + q * 8;
                *(ushort8*)&lh[row * 128 + (c ^ ((row & 7) << 3))] = v;
            }
        } else {
            const float* src = emb + (size_t)id * D_ + half * 64;
#pragma unroll
            for (int q = 0; q < 8; ++q) {
                float4 x0 = *(const float4*)(src + q * 8);
                float4 x1 = *(const float4*)(src + q * 8 + 4);
                ushort8 v;
                v[0] = f2bf(x0.x); v[1] = f2bf(x0.y); v[2] = f2bf(x0.z); v[3] = f2bf(x0.w);
                v[4] = f2bf(x1.x); v[5] = f2bf(x1.y); v[6] = f2bf(x1.z); v[7] = f2bf(x1.w);
                int c = half * 64 + q * 8;
                *(ushort8*)&lh[row * 128 + (c ^ ((row & 7) << 3))] = v;
            }
        }
    }
    __syncthreads();

    int wave = t >> 6, lane = t & 63, lo = lane & 15, hi = lane >> 4;

    // t = h @ a  via mfma 16x16x32 (M=128 rows of h, N=128, K=128)
    f32x4 acc[2][8] = {};
#pragma unroll
    for (int kk = 0; kk < 4; ++kk) {
        int kc = kk * 32 + hi * 8;   // k element offset
        bf16x8 afr[2];
#pragma unroll
        for (int mi = 0; mi < 2; ++mi) {
            int row = wave * 32 + mi * 16 + lo;
            afr[mi] = *(const bf16x8*)&lh[row * 128 + (kc ^ ((row & 7) << 3))];
        }
#pragma unroll
        for (int nj = 0; nj < 8; ++nj) {
            int col = nj * 16 + lo;
            bf16x8 bfr = *(const bf16x8*)(aT + col * 128 + kc);   // L2-resident
            acc[0][nj] = __builtin_amdgcn_mfma_f32_16x16x32_bf16(afr[0], bfr, acc[0][nj], 0, 0, 0);
            acc[1][nj] = __builtin_amdgcn_mfma_f32_16x16x32_bf16(afr[1], bfr, acc[1][nj], 0, 0, 0);
        }
    }

    // e[row] = sum_n tanh(t[row,n]) * bvec[n] ; C/D layout: col=lo, row=hi*4+reg
    float bv[8];
#pragma unroll
    for (int nj = 0; nj < 8; ++nj) bv[nj] = bvec[nj * 16 + lo];
#pragma unroll
    for (int mi = 0; mi < 2; ++mi) {
#pragma unroll
        for (int reg = 0; reg < 4; ++reg) {
            float p = 0.f;
#pragma unroll
            for (int nj = 0; nj < 8; ++nj) p += tanh_fast(acc[mi][nj][reg]) * bv[nj];
            p += __shfl_xor(p, 1); p += __shfl_xor(p, 2);
            p += __shfl_xor(p, 4); p += __shfl_xor(p, 8);
            int row = wave * 32 + mi * 16 + hi * 4 + reg;
            if (lo == 0) l_e[row] = p;
        }
    }
    __syncthreads();

    if (t < 128) {
        float e = l_e[t];
        float at = 0.f;
        if (msk[b * L_ + t]) at = 1.f / (1.f + __expf(-e));
        l_attn[t] = at;
    }
    __syncthreads();

    // user[d] = sum_l attn[l] * h[l][d]
    {
        int d = t & 127, half = t >> 7;
        float s = 0.f;
#pragma unroll 8
        for (int l = half * 64; l < half * 64 + 64; ++l)
            s += l_attn[l] * bf2f(lh[l * 128 + (d ^ ((l & 7) << 3))]);
        l_p[t] = s;
    }
    __syncthreads();
    if (t < 128) {
        float u = l_p[t] + l_p[t + 128];
        user_bf[b * 128 + t] = f2bf(u);
    }
}

// ---------------- kernel 2: logits = user_bf16 @ emb^T + bias ----------------
// grid (2, 391): each block stages one 128-col emb tile ONCE, loops 8 M-tiles.
// MFMA operands swapped vs naive: mfma(emb_frag, user_frag) so each lane's 4
// accumulator regs are 4 consecutive vocab columns -> float4 stores.
__global__ __launch_bounds__(256) void k_logits(
    const unsigned short* __restrict__ user_bf, const float* __restrict__ emb,
    const unsigned short* __restrict__ emb_bf,
    const float* __restrict__ bias, float* __restrict__ out, int use_bf) {
    __shared__ __align__(16) unsigned short lb[128 * 128];  // emb tile [n][k] bf16 swizzled (32KB)

    int t = threadIdx.x;
    int m_base = blockIdx.x * 1024;          // 2 chunks x 8 tiles of 128
    int n0 = blockIdx.y * 128;

    // stage B tile: emb rows n0..n0+127 -> bf16 LDS (guard tail rows -> 0)
    {
        int r = t >> 1, half = t & 1;
        int n = n0 + r;
        if (n < V_) {
            if (use_bf) {
                const unsigned short* src = emb_bf + (size_t)n * D_ + half * 64;
#pragma unroll
                for (int q = 0; q < 8; ++q) {
                    ushort8 v = *(const ushort8*)(src + q * 8);
                    int c = half * 64 + q * 8;
                    *(ushort8*)&lb[r * 128 + (c ^ ((r & 7) << 3))] = v;
                }
            } else {
                const float* src = emb + (size_t)n * D_ + half * 64;
#pragma unroll
                for (int q = 0; q < 8; ++q) {
                    float4 x0 = *(const float4*)(src + q * 8);
                    float4 x1 = *(const float4*)(src + q * 8 + 4);
                    ushort8 v;
                    v[0] = f2bf(x0.x); v[1] = f2bf(x0.y); v[2] = f2bf(x0.z); v[3] = f2bf(x0.w);
                    v[4] = f2bf(x1.x); v[5] = f2bf(x1.y); v[6] = f2bf(x1.z); v[7] = f2bf(x1.w);
                    int c = half * 64 + q * 8;
                    *(ushort8*)&lb[r * 128 + (c ^ ((r & 7) << 3))] = v;
                }
            }
        } else {
            ushort8 z = {0, 0, 0, 0, 0, 0, 0, 0};
#pragma unroll
            for (int q = 0; q < 8; ++q) {
                int c = half * 64 + q * 8;
                *(ushort8*)&lb[r * 128 + (c ^ ((r & 7) << 3))] = z;
            }
        }
    }

    int wave = t >> 6, lane = t & 63, lo = lane & 15, hi = lane >> 4;

    // bias: n = n0 + nj*16 + hi*4 + reg ; amortized over all 8 m-tiles
    float4 bb[8];
#pragma unroll
    for (int nj = 0; nj < 8; ++nj) {
        int n = n0 + nj * 16 + hi * 4;
        if (n + 3 < V_) {
            bb[nj] = *(const float4*)(bias + n);
        } else {
            bb[nj].x = (n + 0 < V_) ? bias[n + 0] : 0.f;
            bb[nj].y = (n + 1 < V_) ? bias[n + 1] : 0.f;
            bb[nj].z = (n + 2 < V_) ? bias[n + 2] : 0.f;
            bb[nj].w = (n + 3 < V_) ? bias[n + 3] : 0.f;
        }
    }
    __syncthreads();

#pragma unroll 1
    for (int mt = 0; mt < 8; ++mt) {
        int m0 = m_base + mt * 128;

        // A (user) fragments from global: 512KB total, L2-resident
        bf16x8 afr[2][4];
#pragma unroll
        for (int mi = 0; mi < 2; ++mi) {
            const unsigned short* ap = user_bf + (size_t)(m0 + wave * 32 + mi * 16 + lo) * 128;
#pragma unroll
            for (int kk = 0; kk < 4; ++kk)
                afr[mi][kk] = *(const bf16x8*)(ap + kk * 32 + hi * 8);
        }

        f32x4 acc[2][8] = {};
#pragma unroll
        for (int kk = 0; kk < 4; ++kk) {
            int kc = kk * 32 + hi * 8;
#pragma unroll
            for (int nj = 0; nj < 8; ++nj) {
                int col = nj * 16 + lo;
                bf16x8 bfr = *(const bf16x8*)&lb[col * 128 + (kc ^ ((col & 7) << 3))];
                // swapped: D[emb_idx][user_idx] -> lane holds 4 consecutive vocab cols
                acc[0][nj] = __builtin_amdgcn_mfma_f32_16x16x32_bf16(bfr, afr[0][kk], acc[0][nj], 0, 0, 0);
                acc[1][nj] = __builtin_amdgcn_mfma_f32_16x16x32_bf16(bfr, afr[1][kk], acc[1][nj], 0, 0, 0);
            }
        }

        // epilogue: row b = lo-derived, 4 consecutive n per lane -> float4 store
#pragma unroll
        for (int mi = 0; mi < 2; ++mi) {
            int b = m0 + wave * 32 + mi * 16 + lo;
#pragma unroll
            for (int nj = 0; nj < 8; ++nj) {
                int n = n0 + nj * 16 + hi * 4;
                float4 o;
                o.x = acc[mi][nj][0] + bb[nj].x;
                o.y = acc[mi][nj][1] + bb[nj].y;
                o.z = acc[mi][nj][2] + bb[nj].z;
                o.w = acc[mi][nj][3] + bb[nj].w;
                if (n + 3 < V_) {
                    *(float4*)(out + (size_t)b * V_ + n) = o;
                } else {
                    if (n + 0 < V_) out[(size_t)b * V_ + n + 0] = o.x;
                    if (n + 1 < V_) out[(size_t)b * V_ + n + 1] = o.y;
                    if (n + 2 < V_) out[(size_t)b * V_ + n + 2] = o.z;
                    if (n + 3 < V_) out[(size_t)b * V_ + n + 3] = o.w;
                }
            }
        }
    }
}

extern "C" void kernel_launch(void* const* d_in, const int* in_sizes, int n_in,
                              void* d_out, int out_size, void* d_ws, size_t ws_size,
                              hipStream_t stream) {
    const int* ids      = (const int*)d_in[0];
    const int* msk      = (const int*)d_in[1];
    const float* emb    = (const float*)d_in[2];
    const float* attn_a = (const float*)d_in[3];
    const float* attn_b = (const float*)d_in[4];
    const float* rbias  = (const float*)d_in[5];
    float* out = (float*)d_out;

    unsigned short* aT      = (unsigned short*)d_ws;                     // 32 KB
    unsigned short* user_bf = (unsigned short*)((char*)d_ws + 32768);    // 512 KB
    unsigned short* emb_bf  = (unsigned short*)((char*)d_ws + 32768 + 524288);  // 12.8 MB
    int use_bf = (ws_size >= (size_t)(32768 + 524288 + 12800000)) ? 1 : 0;

    k_prep<<<64, 256, 0, stream>>>(attn_a, aT);
    if (use_bf) k_convE<<<3125, 256, 0, stream>>>(emb, emb_bf);
    k_user<<<2048, 256, 0, stream>>>(ids, msk, emb, emb_bf, aT, attn_b, user_bf, use_bf);
    k_logits<<<dim3(2, (V_ + 127) / 128), 256, 0, stream>>>(user_bf, emb, emb_bf, rbias, out, use_bf);
}